// Round 6
// baseline (164.825 us; speedup 1.0000x reference)
//
#include <hip/hip_runtime.h>
#include <hip/hip_fp16.h>

#define IN_F 4096
#define OUT_F 11008
#define FP_F 256
#define NROWS 512
#define BN 64
#define BM 128
#define PBLK (OUT_F / 16)                    // 688 pack blocks
#define NGEMM ((OUT_F / BN) * (NROWS / BM))  // 172 * 4 = 688

typedef int v4i __attribute__((ext_vector_type(4)));
typedef int v16i __attribute__((ext_vector_type(16)));
typedef float v4f __attribute__((ext_vector_type(4)));
typedef float v16f __attribute__((ext_vector_type(16)));
typedef _Float16 half8 __attribute__((ext_vector_type(8)));

__device__ __forceinline__ int pack4(v4i a) {
  return (int)((unsigned)(a[0] & 255) | ((unsigned)(a[1] & 255) << 8) |
               ((unsigned)(a[2] & 255) << 16) | ((unsigned)(a[3] & 255) << 24));
}

// 32x32 fragment layout for int8 operand, K-chunks of 32:
//   chunk (g = row>>5, kb32 = k>>5), flat v4i slot = (g*128 + kb32)*64 + lane,
//   lane = (row&31) + 32*((k>>4)&1), byte = k&15.
// Matches mfma_*_32x32x* operand mapping: lane l holds row l&31, k = (l>>5)*16 + j.

// Fused prep: blocks [0,NROWS) quantize x rows -> qx; blocks [NROWS,NROWS+PBLK)
// pack q_weight int32 -> int8 qb. Reads 1KB contiguous per wave instruction.
__global__ __launch_bounds__(256) void prep_kernel(
    const float* __restrict__ x, const int* __restrict__ ind,
    const int* __restrict__ qw, signed char* __restrict__ qx,
    _Float16* __restrict__ act, float* __restrict__ xscale,
    signed char* __restrict__ qb)
{
  const int t = threadIdx.x;
  if (blockIdx.x < NROWS) {
    // ---------------- quant ----------------
    const int m = blockIdx.x;
    __shared__ unsigned char zm[IN_F];
    __shared__ float wmax[4];
    int* zmi = (int*)zm;
    #pragma unroll
    for (int i = 0; i < IN_F / 4 / 256; ++i) zmi[t + i * 256] = 0;
    __syncthreads();
    const int idx = ind[t];
    zm[idx] = 1;
    __syncthreads();

    const float* xr = x + (size_t)m * IN_F;
    float v[16];
    float amax = 0.f;
    const int k0 = t * 16;
    #pragma unroll
    for (int q = 0; q < 4; ++q) {
      v4f f = *(const v4f*)(xr + k0 + q * 4);
      #pragma unroll
      for (int j = 0; j < 4; ++j) {
        float mv = zm[k0 + q * 4 + j] ? 0.f : f[j];
        v[q * 4 + j] = mv;
        amax = fmaxf(amax, fabsf(mv));
      }
    }
    #pragma unroll
    for (int off = 32; off >= 1; off >>= 1)
      amax = fmaxf(amax, __shfl_xor(amax, off));
    if ((t & 63) == 0) wmax[t >> 6] = amax;
    __syncthreads();
    amax = fmaxf(fmaxf(wmax[0], wmax[1]), fmaxf(wmax[2], wmax[3]));
    const float scale = fmaxf(amax / 127.0f, 1e-8f);
    if (t == 0) xscale[m] = scale;
    const float inv = 1.0f / scale;

    union { signed char b[16]; v4i w4; } pk;
    #pragma unroll
    for (int j = 0; j < 16; ++j) {
      float qv = rintf(v[j] * inv);            // round-half-even, like jnp.round
      qv = fminf(fmaxf(qv, -128.f), 127.f);
      pk.b[j] = (signed char)qv;
    }
    // k0 = t*16 -> kb32 = t>>1, klane = t&1
    ((v4i*)qx)[((m >> 5) * 128 + (t >> 1)) * 64 + (m & 31) + 32 * (t & 1)] = pk.w4;

    act[m * FP_F + t] = (_Float16)xr[idx];
  } else {
    // ---------------- pack ----------------
    const int p = blockIdx.x - NROWS;          // 16-row group
    const int* src = qw + (size_t)p * 16 * IN_F + t * 4;
    int* qbi = (int*)qb;
    const int sub = (t >> 2) & 1;              // (k4>>4)&1 with k4 = c*1024 + t*4
    const int lbase = ((p & 1) * 16 + 32 * sub) * 4 + (t & 3);
    #pragma unroll 4
    for (int it = 0; it < 64; ++it) {
      const int rr = it >> 2;                  // row within group
      const int c  = it & 3;                   // 1024-int quarter
      v4i v = *(const v4i*)(src + (size_t)rr * IN_F + c * 1024);
      const int kb32 = c * 32 + (t >> 3);
      qbi[((p >> 1) * 128 + kb32) * 256 + rr * 4 + lbase] = pack4(v);
    }
  }
}

// GEMM: 128(M) x 64(N) tile, 4 waves; wave w owns rows [row0,row0+32) x 64 cols
// using 32x32x32 i8 MFMA (2x arithmetic intensity vs 16x16x64).
// No LDS, no barriers; 64-k iterations, depth-3 register ring (prefetch it+2).
__global__ __launch_bounds__(256, 3) void gemm_kernel(
    const signed char* __restrict__ qx, const signed char* __restrict__ qb,
    const float* __restrict__ scol, const float* __restrict__ wc,
    const float* __restrict__ bias, const _Float16* __restrict__ act,
    const float* __restrict__ xscale, float* __restrict__ out)
{
  const int tid = threadIdx.x;
  const int w = tid >> 6;
  const int l = tid & 63;
  // bijective XCD swizzle (688 = 8*86): 4 msegs of an ntile adjacent on one XCD
  const int orig = blockIdx.x;
  const int wgid = (orig & 7) * 86 + (orig >> 3);
  const int mseg = wgid & 3;
  const int ntile = wgid >> 2;
  const int n0 = ntile * BN;
  const int row0 = mseg * BM + w * 32;

  const v4i* qx4 = (const v4i*)qx;
  const v4i* qb4 = (const v4i*)qb;
  const int aBase  = ((mseg * 4 + w) * 128) * 64 + l;       // + kb32*64
  const int b0Base = (((n0 >> 5) + 0) * 128) * 64 + l;
  const int b1Base = (((n0 >> 5) + 1) * 128) * 64 + l;

  v4i a[3][2], b[3][4];     // slot s: iteration's 2 k-chunks; b[s][q*2+nf]
  #pragma unroll
  for (int s = 0; s < 2; ++s) {
    #pragma unroll
    for (int q = 0; q < 2; ++q) {
      a[s][q]         = qx4[aBase  + (2 * s + q) * 64];
      b[s][q * 2 + 0] = qb4[b0Base + (2 * s + q) * 64];
      b[s][q * 2 + 1] = qb4[b1Base + (2 * s + q) * 64];
    }
  }

  v16i acc[2] = {};

#define ITER(IT, S) do {                                                      \
    const int kf = ((IT) + 2 < 64) ? (IT) + 2 : 63;                           \
    const int SP = ((S) + 2) % 3;                                             \
    _Pragma("unroll")                                                         \
    for (int q = 0; q < 2; ++q) {                                             \
      a[SP][q]         = qx4[aBase  + (2 * kf + q) * 64];                     \
      b[SP][q * 2 + 0] = qb4[b0Base + (2 * kf + q) * 64];                     \
      b[SP][q * 2 + 1] = qb4[b1Base + (2 * kf + q) * 64];                     \
    }                                                                         \
    _Pragma("unroll")                                                         \
    for (int q = 0; q < 2; ++q)                                               \
      _Pragma("unroll")                                                       \
      for (int nf = 0; nf < 2; ++nf)                                          \
        acc[nf] = __builtin_amdgcn_mfma_i32_32x32x32_i8(                      \
            a[S][q], b[S][q * 2 + nf], acc[nf], 0, 0, 0);                     \
  } while (0)

  for (int i = 0; i < 63; i += 3) {
    ITER(i + 0, 0);
    ITER(i + 1, 1);
    ITER(i + 2, 2);
  }
  ITER(63, 0);
#undef ITER

  // epilogue scales: C/D 32x32 mapping: col = l&31, row = (r&3)+8*(r>>2)+4*(l>>5)
  float sc[2], bs[2];
  #pragma unroll
  for (int nf = 0; nf < 2; ++nf) {
    sc[nf] = scol[n0 + nf * 32 + (l & 31)];
    bs[nf] = bias[n0 + nf * 32 + (l & 31)];
  }
  const int hi4 = 4 * (l >> 5);
  float xs[16];
  #pragma unroll
  for (int r = 0; r < 16; ++r)
    xs[r] = xscale[row0 + (r & 3) + 8 * (r >> 2) + hi4];

  v16f facc[2];
  #pragma unroll
  for (int nf = 0; nf < 2; ++nf)
    #pragma unroll
    for (int r = 0; r < 16; ++r)
      facc[nf][r] = (float)acc[nf][r] * xs[r] * sc[nf];

  // outlier fp phase: K=256 in 16 steps of 16, 32x32x16 f16 MFMA
  const int arow = row0 + (l & 31);
  #pragma unroll
  for (int ks = 0; ks < 16; ++ks) {
    const int kk = ks * 16 + (l >> 5) * 8;
    half8 ah = *(const half8*)(act + arow * FP_F + kk);
    half8 bh[2];
    #pragma unroll
    for (int nf = 0; nf < 2; ++nf) {
      const float* wr = wc + (size_t)(n0 + nf * 32 + (l & 31)) * FP_F + kk;
      v4f w0 = *(const v4f*)(wr);
      v4f w1 = *(const v4f*)(wr + 4);
      half8 hb;
      #pragma unroll
      for (int j = 0; j < 4; ++j) {
        hb[j] = (_Float16)w0[j];
        hb[4 + j] = (_Float16)w1[j];
      }
      bh[nf] = hb;
    }
    #pragma unroll
    for (int nf = 0; nf < 2; ++nf)
      facc[nf] = __builtin_amdgcn_mfma_f32_32x32x16_f16(ah, bh[nf], facc[nf], 0, 0, 0);
  }

  #pragma unroll
  for (int nf = 0; nf < 2; ++nf) {
    const int col = n0 + nf * 32 + (l & 31);
    #pragma unroll
    for (int r = 0; r < 16; ++r) {
      const int row = row0 + (r & 3) + 8 * (r >> 2) + hi4;
      out[(size_t)row * OUT_F + col] = facc[nf][r] + bs[nf];
    }
  }
}

extern "C" void kernel_launch(void* const* d_in, const int* in_sizes, int n_in,
                              void* d_out, int out_size, void* d_ws, size_t ws_size,
                              hipStream_t stream) {
  const float* x      = (const float*)d_in[0];
  const int*   qw     = (const int*)d_in[1];
  const float* scol   = (const float*)d_in[2];
  const float* wcache = (const float*)d_in[3];
  const int*   ind    = (const int*)d_in[4];
  const float* bias   = (const float*)d_in[5];
  float* out = (float*)d_out;

  const size_t qx_off  = 0;
  const size_t act_off = (size_t)NROWS * IN_F;                      // 2 MB
  const size_t xs_off  = act_off + (size_t)NROWS * FP_F * 2;        // +256 KB
  const size_t qb_off  = xs_off + (size_t)NROWS * 4;                // +2 KB

  signed char* qx = (signed char*)d_ws + qx_off;
  _Float16* act   = (_Float16*)((char*)d_ws + act_off);
  float* xscale   = (float*)((char*)d_ws + xs_off);
  signed char* qb = (signed char*)d_ws + qb_off;

  prep_kernel<<<NROWS + PBLK, 256, 0, stream>>>(x, ind, qw, qx, act, xscale, qb);
  gemm_kernel<<<NGEMM, 256, 0, stream>>>(qx, qb, scol, wcache, bias, act, xscale, out);
}

// Round 7
// 119.468 us; speedup vs baseline: 1.3797x; 1.3797x over previous
//
#include <hip/hip_runtime.h>
#include <hip/hip_fp16.h>

#define IN_F 4096
#define OUT_F 11008
#define FP_F 256
#define NROWS 512
#define BN 32
#define BM 256
#define PBLK (OUT_F / 16)                    // 688 pack blocks (32 rows x K/2 each)
#define NGEMM ((OUT_F / BN) * (NROWS / BM))  // 344 * 2 = 688

typedef int v4i __attribute__((ext_vector_type(4)));
typedef int v16i __attribute__((ext_vector_type(16)));
typedef float v4f __attribute__((ext_vector_type(4)));
typedef float v16f __attribute__((ext_vector_type(16)));
typedef _Float16 half8 __attribute__((ext_vector_type(8)));

__device__ __forceinline__ int pack4(v4i a) {
  return (int)((unsigned)(a[0] & 255) | ((unsigned)(a[1] & 255) << 8) |
               ((unsigned)(a[2] & 255) << 16) | ((unsigned)(a[3] & 255) << 24));
}

// 32x32 int8 fragment layout (verified in round 6): v4i slot =
//   (g*128 + kb32)*64 + lane, lane = (row&31) + 32*((k>>4)&1), byte = k&15.
// A lane's 16 B = 16 CONSECUTIVE k of one row -> packable from a 64B
// contiguous per-lane read of q_weight.

// Fused prep. Blocks [0, PBLK): pack q_weight int32 -> int8 qb.
// Blocks [PBLK, PBLK+NROWS): quantize x rows -> qx + act + xscale.
__global__ __launch_bounds__(256) void prep_kernel(
    const float* __restrict__ x, const int* __restrict__ ind,
    const int* __restrict__ qw, signed char* __restrict__ qx,
    _Float16* __restrict__ act, float* __restrict__ xscale,
    signed char* __restrict__ qb)
{
  const int t = threadIdx.x;
  if (blockIdx.x < PBLK) {
    // ---------------- pack: 32 rows x 2048 ints per block ----------------
    const int p = blockIdx.x;
    const int g = p >> 1;                 // 32-row group
    const int khalf = p & 1;              // which K half
    const int w = t >> 6;
    const int l = t & 63;
    const int row = g * 32 + (l & 31);
    const int kb0 = khalf * 64 + w * 16;  // wave's 16 kb32 chunks
    const int* src = qw + (size_t)row * IN_F + (l >> 5) * 16;
    v4i* qb4v = (v4i*)qb;
    const size_t dBase = ((size_t)g * 128 + kb0) * 64 + l;

    v4i r[4][4];                          // depth-4 ring
    #pragma unroll
    for (int s = 0; s < 3; ++s) {
      const int* sp = src + (kb0 + s) * 32;
      #pragma unroll
      for (int j = 0; j < 4; ++j) r[s][j] = *(const v4i*)(sp + j * 4);
    }
#define PITER(I, S) do {                                                      \
      const int kn = ((I) + 3 < 16) ? (I) + 3 : 15;                           \
      const int SP = ((S) + 3) & 3;                                           \
      const int* sp = src + (kb0 + kn) * 32;                                  \
      _Pragma("unroll")                                                       \
      for (int j = 0; j < 4; ++j) r[SP][j] = *(const v4i*)(sp + j * 4);       \
      v4i pk;                                                                 \
      _Pragma("unroll")                                                       \
      for (int j = 0; j < 4; ++j) pk[j] = pack4(r[S][j]);                     \
      qb4v[dBase + (size_t)(I) * 64] = pk;                                    \
    } while (0)
    for (int i = 0; i < 16; i += 4) {
      PITER(i + 0, 0);
      PITER(i + 1, 1);
      PITER(i + 2, 2);
      PITER(i + 3, 3);
    }
#undef PITER
  } else {
    // ---------------- quant ----------------
    const int m = blockIdx.x - PBLK;
    __shared__ unsigned char zm[IN_F];
    __shared__ float wmax[4];
    int* zmi = (int*)zm;
    #pragma unroll
    for (int i = 0; i < IN_F / 4 / 256; ++i) zmi[t + i * 256] = 0;
    __syncthreads();
    const int idx = ind[t];
    zm[idx] = 1;
    __syncthreads();

    const float* xr = x + (size_t)m * IN_F;
    float v[16];
    float amax = 0.f;
    const int k0 = t * 16;
    #pragma unroll
    for (int q = 0; q < 4; ++q) {
      v4f f = *(const v4f*)(xr + k0 + q * 4);
      #pragma unroll
      for (int j = 0; j < 4; ++j) {
        float mv = zm[k0 + q * 4 + j] ? 0.f : f[j];
        v[q * 4 + j] = mv;
        amax = fmaxf(amax, fabsf(mv));
      }
    }
    #pragma unroll
    for (int off = 32; off >= 1; off >>= 1)
      amax = fmaxf(amax, __shfl_xor(amax, off));
    if ((t & 63) == 0) wmax[t >> 6] = amax;
    __syncthreads();
    amax = fmaxf(fmaxf(wmax[0], wmax[1]), fmaxf(wmax[2], wmax[3]));
    const float scale = fmaxf(amax / 127.0f, 1e-8f);
    if (t == 0) xscale[m] = scale;
    const float inv = 1.0f / scale;

    union { signed char b[16]; v4i w4; } pk;
    #pragma unroll
    for (int j = 0; j < 16; ++j) {
      float qv = rintf(v[j] * inv);            // round-half-even, like jnp.round
      qv = fminf(fmaxf(qv, -128.f), 127.f);
      pk.b[j] = (signed char)qv;
    }
    // k0 = t*16 -> kb32 = t>>1, khalf = t&1
    ((v4i*)qx)[((m >> 5) * 128 + (t >> 1)) * 64 + (m & 31) + 32 * (t & 1)] = pk.w4;

    act[m * FP_F + t] = (_Float16)xr[idx];
  }
}

// GEMM: 256(M) x 32(N) tile, 4 waves; wave w owns rows [row0,row0+64) x 32 cols
// as 2 m-frags of 32x32x32 i8 MFMA. No LDS, no barriers; 64 k-iterations
// (2 k-chunks each), depth-3 register ring. qb read 2x total (2nd pass L3-hit).
__global__ __launch_bounds__(256, 3) void gemm_kernel(
    const signed char* __restrict__ qx, const signed char* __restrict__ qb,
    const float* __restrict__ scol, const float* __restrict__ wc,
    const float* __restrict__ bias, const _Float16* __restrict__ act,
    const float* __restrict__ xscale, float* __restrict__ out)
{
  const int tid = threadIdx.x;
  const int w = tid >> 6;
  const int l = tid & 63;
  // bijective XCD swizzle (688 = 8*86): the 2 msegs of an ntile are
  // consecutive wgids on one XCD -> qb panel L2/L3-hits on second read.
  const int orig = blockIdx.x;
  const int wgid = (orig & 7) * 86 + (orig >> 3);
  const int mseg = wgid & 1;
  const int ntile = wgid >> 1;
  const int n0 = ntile * BN;
  const int row0 = mseg * BM + w * 64;

  const v4i* qx4 = (const v4i*)qx;
  const v4i* qb4 = (const v4i*)qb;
  const int aB0 = ((mseg * 8 + w * 2 + 0) * 128) * 64 + l;  // + kb32*64
  const int aB1 = ((mseg * 8 + w * 2 + 1) * 128) * 64 + l;
  const int bBase = (ntile * 128) * 64 + l;

  v4i a[3][2][2];   // [slot][chunk q][mf]
  v4i b[3][2];      // [slot][chunk q]
  #pragma unroll
  for (int s = 0; s < 2; ++s) {
    #pragma unroll
    for (int q = 0; q < 2; ++q) {
      const int c = 2 * s + q;
      a[s][q][0] = qx4[aB0 + c * 64];
      a[s][q][1] = qx4[aB1 + c * 64];
      b[s][q]    = qb4[bBase + c * 64];
    }
  }

  v16i acc[2] = {};

#define ITER(IT, S) do {                                                      \
    const int kf = ((IT) + 2 < 64) ? (IT) + 2 : 63;                           \
    const int SP = ((S) + 2) % 3;                                             \
    _Pragma("unroll")                                                         \
    for (int q = 0; q < 2; ++q) {                                             \
      const int c = 2 * kf + q;                                               \
      a[SP][q][0] = qx4[aB0 + c * 64];                                        \
      a[SP][q][1] = qx4[aB1 + c * 64];                                        \
      b[SP][q]    = qb4[bBase + c * 64];                                      \
    }                                                                         \
    _Pragma("unroll")                                                         \
    for (int q = 0; q < 2; ++q)                                               \
      _Pragma("unroll")                                                       \
      for (int mf = 0; mf < 2; ++mf)                                          \
        acc[mf] = __builtin_amdgcn_mfma_i32_32x32x32_i8(                      \
            a[S][q][mf], b[S][q], acc[mf], 0, 0, 0);                          \
  } while (0)

  for (int i = 0; i < 63; i += 3) {
    ITER(i + 0, 0);
    ITER(i + 1, 1);
    ITER(i + 2, 2);
  }
  ITER(63, 0);
#undef ITER

  // epilogue: C/D 32x32 mapping: col = l&31, row = (r&3)+8*(r>>2)+4*(l>>5)
  const float sc = scol[n0 + (l & 31)];
  const float bs = bias[n0 + (l & 31)];
  const int hi4 = 4 * (l >> 5);
  float xs[2][16];
  #pragma unroll
  for (int mf = 0; mf < 2; ++mf)
    #pragma unroll
    for (int r = 0; r < 16; ++r)
      xs[mf][r] = xscale[row0 + mf * 32 + (r & 3) + 8 * (r >> 2) + hi4];

  v16f facc[2];
  #pragma unroll
  for (int mf = 0; mf < 2; ++mf)
    #pragma unroll
    for (int r = 0; r < 16; ++r)
      facc[mf][r] = (float)acc[mf][r] * xs[mf][r] * sc;

  // outlier fp phase: K=256 in 16 steps of 16, 32x32x16 f16 MFMA
  #pragma unroll
  for (int ks = 0; ks < 16; ++ks) {
    const int kk = ks * 16 + (l >> 5) * 8;
    half8 ah[2];
    #pragma unroll
    for (int mf = 0; mf < 2; ++mf) {
      const int arow = row0 + mf * 32 + (l & 31);
      ah[mf] = *(const half8*)(act + arow * FP_F + kk);
    }
    const float* wr = wc + (size_t)(n0 + (l & 31)) * FP_F + kk;
    v4f w0 = *(const v4f*)(wr);
    v4f w1 = *(const v4f*)(wr + 4);
    half8 bh;
    #pragma unroll
    for (int j = 0; j < 4; ++j) {
      bh[j] = (_Float16)w0[j];
      bh[4 + j] = (_Float16)w1[j];
    }
    #pragma unroll
    for (int mf = 0; mf < 2; ++mf)
      facc[mf] = __builtin_amdgcn_mfma_f32_32x32x16_f16(ah[mf], bh, facc[mf], 0, 0, 0);
  }

  const int col = n0 + (l & 31);
  #pragma unroll
  for (int mf = 0; mf < 2; ++mf)
    #pragma unroll
    for (int r = 0; r < 16; ++r) {
      const int row = row0 + mf * 32 + (r & 3) + 8 * (r >> 2) + hi4;
      out[(size_t)row * OUT_F + col] = facc[mf][r] + bs;
    }
}

extern "C" void kernel_launch(void* const* d_in, const int* in_sizes, int n_in,
                              void* d_out, int out_size, void* d_ws, size_t ws_size,
                              hipStream_t stream) {
  const float* x      = (const float*)d_in[0];
  const int*   qw     = (const int*)d_in[1];
  const float* scol   = (const float*)d_in[2];
  const float* wcache = (const float*)d_in[3];
  const int*   ind    = (const int*)d_in[4];
  const float* bias   = (const float*)d_in[5];
  float* out = (float*)d_out;

  const size_t qx_off  = 0;
  const size_t act_off = (size_t)NROWS * IN_F;                      // 2 MB
  const size_t xs_off  = act_off + (size_t)NROWS * FP_F * 2;        // +256 KB
  const size_t qb_off  = xs_off + (size_t)NROWS * 4;                // +2 KB

  signed char* qx = (signed char*)d_ws + qx_off;
  _Float16* act   = (_Float16*)((char*)d_ws + act_off);
  float* xscale   = (float*)((char*)d_ws + xs_off);
  signed char* qb = (signed char*)d_ws + qb_off;

  prep_kernel<<<PBLK + NROWS, 256, 0, stream>>>(x, ind, qw, qx, act, xscale, qb);
  gemm_kernel<<<NGEMM, 256, 0, stream>>>(qx, qb, scol, wcache, bias, act, xscale, out);
}